// Round 11
// baseline (186.677 us; speedup 1.0000x reference)
//
#include <hip/hip_runtime.h>
#include <hip/hip_bf16.h>

// Problem constants: B=16, S=1024, D=768, DOUT=256
static constexpr float INV_TEMP = 0.03608439182435161f; // 1/sqrt(768)

typedef __attribute__((ext_vector_type(8))) short bf16x8;
typedef __attribute__((ext_vector_type(4))) float f32x4;
typedef __attribute__((ext_vector_type(8))) unsigned short u16x8;
typedef __attribute__((ext_vector_type(4))) unsigned short u16x4;

__device__ __forceinline__ unsigned short f2bf(float f) {
  unsigned u = __float_as_uint(f);
  u += 0x7fffu + ((u >> 16) & 1u);
  return (unsigned short)(u >> 16);
}
__device__ __forceinline__ float bf2f(unsigned short h) {
  return __uint_as_float((unsigned)h << 16);
}

__device__ __forceinline__ void async_copy16(const void* g, void* lds) {
  __builtin_amdgcn_global_load_lds(
      (const __attribute__((address_space(1))) unsigned int*)g,
      (__attribute__((address_space(3))) unsigned int*)lds, 16, 0, 0);
}

// ---------------- pack: emb -> bf16 into QKE cols 768..1535 (row stride 1536) ----------------
__global__ __launch_bounds__(256) void pack_emb(const float* __restrict__ src,
                                                unsigned short* __restrict__ QKE) {
  long i = ((long)blockIdx.x * 256 + threadIdx.x) * 8;
  const long row = i / 768, col = i % 768;
  float4 a = *(const float4*)(src + i);
  float4 b = *(const float4*)(src + i + 4);
  u16x8 v;
  v[0] = f2bf(a.x); v[1] = f2bf(a.y); v[2] = f2bf(a.z); v[3] = f2bf(a.w);
  v[4] = f2bf(b.x); v[5] = f2bf(b.y); v[6] = f2bf(b.z); v[7] = f2bf(b.w);
  *(u16x8*)(QKE + row * 1536 + 768 + col) = v;
}

// ---- pack: select projection set; Wq_bf/Wk_bf straight-cast; WvT transpose; bias_v ----
__global__ __launch_bounds__(256) void pack_sel(
    const int* __restrict__ isq_p,
    const float* qWq, const float* qWk, const float* qWv, const float* qbv,
    const float* dWq, const float* dWk, const float* dWv, const float* dbv,
    unsigned short* __restrict__ Wq_bf,   // [768][768]
    unsigned short* __restrict__ Wk_bf,   // [768][768]
    unsigned short* __restrict__ WvTe,    // [384][768]; rows 0..255 = Wv^T
    float* __restrict__ bias_v) {         // [384]
  const int b = blockIdx.x, t = threadIdx.x;
  const int isq = *isq_p;
  if (b < 1152) {
    const int which = b >= 576;
    const float* W = which ? (isq ? qWk : dWk) : (isq ? qWq : dWq);
    unsigned short* o = which ? Wk_bf : Wq_bf;
    const long i = ((long)(which ? b - 576 : b) * 256 + t) * 4;
    float4 x = *(const float4*)(W + i);
    u16x4 y; y[0] = f2bf(x.x); y[1] = f2bf(x.y); y[2] = f2bf(x.z); y[3] = f2bf(x.w);
    *(u16x4*)(o + i) = y;
  } else if (b < 1344) {  // WvTe[n][d] = Wv[d][n]
    const float* Wv = isq ? qWv : dWv;
    const long base = ((long)(b - 1152) * 256 + t) * 4;
#pragma unroll
    for (int j = 0; j < 4; ++j) {
      long o = base + j;
      int n = (int)(o / 768), d = (int)(o % 768);
      WvTe[o] = f2bf(Wv[(long)d * 256 + n]);
    }
  } else {
    const float* bv = isq ? qbv : dbv;
    if (t < 256) bias_v[t] = bv[t];
  }
}

// ---- G GEMM: Gt[m][n] = sum_a Wk[m,a]*Wq[n,a]  (64x64 tiles, BK=32) ----
__global__ __launch_bounds__(256) void gemm_g(
    const unsigned short* __restrict__ Wk_bf,
    const unsigned short* __restrict__ Wq_bf,
    unsigned short* __restrict__ Gt) {         // [768][768]
  __shared__ unsigned short Ab[2][64 * 32];
  __shared__ unsigned short Bb[2][64 * 32];
  const int tid = threadIdx.x, wid = tid >> 6, lane = tid & 63;
  const unsigned short* A = Wk_bf + (long)blockIdx.x * 64 * 768;
  const unsigned short* BT = Wq_bf + (long)blockIdx.y * 64 * 768;

  auto stage = [&](int buf, int kt) {
    const int e = tid * 8, row = e >> 5, col = e & 31;
    async_copy16(A + (long)row * 768 + kt * 32 + col, &Ab[buf][e]);
    async_copy16(BT + (long)row * 768 + kt * 32 + col, &Bb[buf][e]);
  };

  f32x4 acc[2][2] = {};
  stage(0, 0);
  __syncthreads();
  int buf = 0;
  const int wr = wid >> 1, wc = wid & 1;
  const int fr = lane & 15, fq = lane >> 4;
  for (int kt = 0; kt < 24; ++kt) {
    if (kt + 1 < 24) stage(buf ^ 1, kt + 1);
    const unsigned short* Ap = &Ab[buf][(wr * 32 + fr) * 32 + fq * 8];
    const unsigned short* Bp = &Bb[buf][(wc * 32 + fr) * 32 + fq * 8];
    bf16x8 a[2], b[2];
#pragma unroll
    for (int mi = 0; mi < 2; ++mi) a[mi] = *(const bf16x8*)(Ap + mi * 16 * 32);
#pragma unroll
    for (int ni = 0; ni < 2; ++ni) b[ni] = *(const bf16x8*)(Bp + ni * 16 * 32);
#pragma unroll
    for (int mi = 0; mi < 2; ++mi)
#pragma unroll
      for (int ni = 0; ni < 2; ++ni)
        acc[mi][ni] = __builtin_amdgcn_mfma_f32_16x16x32_bf16(a[mi], b[ni], acc[mi][ni], 0, 0, 0);
    __syncthreads();
    buf ^= 1;
  }
#pragma unroll
  for (int mi = 0; mi < 2; ++mi)
#pragma unroll
    for (int ni = 0; ni < 2; ++ni) {
      const long m = (long)blockIdx.x * 64 + wr * 32 + mi * 16 + fq * 4;
      const long n = (long)blockIdx.y * 64 + wc * 32 + ni * 16 + fr;
      f32x4 v = acc[mi][ni];
#pragma unroll
      for (int r = 0; r < 4; ++r) Gt[(m + r) * 768 + n] = f2bf(v[r]);
    }
}

// ---- uvc_fast: WvTe[256]=u (Wq.bk), WvTe[257]=v (Wk.bq); bias_v[256]=c, [257..383]=0 ----
__global__ __launch_bounds__(256) void uvc_fast(
    const int* __restrict__ isq_p,
    const float* qWq, const float* qbq, const float* qWk, const float* qbk,
    const float* dWq, const float* dbq, const float* dWk, const float* dbk,
    unsigned short* __restrict__ WvTe, float* __restrict__ bias_v) {
  const int b = blockIdx.x, t = threadIdx.x;
  const int isq = *isq_p;
  const float* Wq = isq ? qWq : dWq;  const float* bq = isq ? qbq : dbq;
  const float* Wk = isq ? qWk : dWk;  const float* bk = isq ? qbk : dbk;
  __shared__ float red[256];
  if (b < 1536) {
    const int lo = (b < 768);
    const int d = lo ? b : b - 768;
    const float* W = lo ? Wq : Wk;
    const float* bvec = lo ? bk : bq;
    float s = 0.f;
#pragma unroll
    for (int i = 0; i < 3; ++i) {
      const int a = t + i * 256;
      s += W[(long)d * 768 + a] * bvec[a];
    }
    red[t] = s;
    __syncthreads();
    for (int off = 128; off; off >>= 1) {
      if (t < off) red[t] += red[t + off];
      __syncthreads();
    }
    if (t == 0) WvTe[(long)(lo ? 256 : 257) * 768 + d] = f2bf(red[0]);
  } else {
    if (t < 128) bias_v[256 + t] = 0.f;
    float p = 0.f;
    for (int a = t; a < 768; a += 256) p += bq[a] * bk[a];
    red[t] = p;
    __syncthreads();
    for (int off = 128; off; off >>= 1) {
      if (t < off) red[t] += red[t + off];
      __syncthreads();
    }
    if (t == 0) bias_v[256] = red[0];
  }
}

// ============ tproj2: QKE cols 0..767 = emb * Gt^T  (2-phase 128^2, XCD-chunked) ============
// f in [0,768): kx=f&7, c=f>>3 in [0,96); nt=c>>4 (0..5), mt=16*kx+(c&15) (0..127).
__global__ __launch_bounds__(256) void tproj2(
    unsigned short* __restrict__ QKE,
    const unsigned short* __restrict__ Gt) {
  __shared__ unsigned short Ab[2][128 * 32];
  __shared__ unsigned short Bb[2][128 * 32];
  const int tid = threadIdx.x, wid = tid >> 6, lane = tid & 63;
  const int f = blockIdx.x;
  const int kx = f & 7, c = f >> 3;
  const long nt = c >> 4;
  const long mt = 16 * kx + (c & 15);
  const unsigned short* A = QKE + 768 + mt * 128 * 1536;  // emb view, ld 1536
  const unsigned short* BT = Gt + nt * 128 * 768;         // ld 768
  const int srow = lane >> 2;
  const int skk = (lane & 3) * 8;

  auto stage = [&](int buf, int kt) {
    const unsigned short* As = A + (long)kt * 32;
    const unsigned short* Bs = BT + (long)kt * 32;
#pragma unroll
    for (int i = 0; i < 2; ++i) {
      int ch = wid * 2 + i;
      async_copy16(As + (long)(ch * 16 + srow) * 1536 + skk, &Ab[buf][ch * 512]);
      async_copy16(Bs + (long)(ch * 16 + srow) * 768 + skk, &Bb[buf][ch * 512]);
    }
  };

  f32x4 acc[4][4] = {};
  stage(0, 0);
  __syncthreads();
  int buf = 0;
  const int wr = wid >> 1, wc = wid & 1;
  const int fr = lane & 15, fq = lane >> 4;
  for (int kt = 0; kt < 24; ++kt) {
    if (kt + 1 < 24) stage(buf ^ 1, kt + 1);
    const unsigned short* Ap = &Ab[buf][(wr * 64 + fr) * 32 + fq * 8];
    const unsigned short* Bp = &Bb[buf][(wc * 64 + fr) * 32 + fq * 8];
    bf16x8 af[4], bfv[4];
#pragma unroll
    for (int mi = 0; mi < 4; ++mi) af[mi] = *(const bf16x8*)(Ap + mi * 16 * 32);
#pragma unroll
    for (int ni = 0; ni < 4; ++ni) bfv[ni] = *(const bf16x8*)(Bp + ni * 16 * 32);
#pragma unroll
    for (int mi = 0; mi < 4; ++mi)
#pragma unroll
      for (int ni = 0; ni < 4; ++ni)
        acc[mi][ni] = __builtin_amdgcn_mfma_f32_16x16x32_bf16(af[mi], bfv[ni], acc[mi][ni], 0, 0, 0);
    __syncthreads();
    buf ^= 1;
  }
#pragma unroll
  for (int mi = 0; mi < 4; ++mi)
#pragma unroll
    for (int ni = 0; ni < 4; ++ni) {
      const long m = mt * 128 + wr * 64 + mi * 16 + fq * 4;
      const long n = nt * 128 + wc * 64 + ni * 16 + fr;
      f32x4 v = acc[mi][ni];
#pragma unroll
      for (int r = 0; r < 4; ++r) QKE[(m + r) * 1536 + n] = f2bf(v[r]);
    }
}

// ============ logits2: S = (T*emb^T + rvec_i + cvec_j)*INV_TEMP (2-phase 128^2) ============
// f in [0,1024): kx=f&7, c=f>>3 in [0,128); bz=2kx+(c>>6); i2=c&63; by=i2>>3, bx=i2&7.
__global__ __launch_bounds__(256) void logits2(
    const unsigned short* __restrict__ QKE,
    const unsigned short* __restrict__ VTe,
    float* __restrict__ attn) {
  __shared__ unsigned short Ab[2][128 * 32];
  __shared__ unsigned short Bb[2][128 * 32];
  const int tid = threadIdx.x, wid = tid >> 6, lane = tid & 63;
  const int f = blockIdx.x;
  const int kx = f & 7, c = f >> 3;
  const int bz = 2 * kx + (c >> 6);
  const int i2 = c & 63, by = i2 >> 3, bx = i2 & 7;
  const unsigned short* A = QKE + (long)bz * 1024 * 1536 + (long)bx * 128 * 1536;        // T cols
  const unsigned short* BT = QKE + 768 + (long)bz * 1024 * 1536 + (long)by * 128 * 1536; // emb cols
  const int srow = lane >> 2;
  const int skk = (lane & 3) * 8;

  auto stage = [&](int buf, int kt) {
    const unsigned short* As = A + (long)kt * 32;
    const unsigned short* Bs = BT + (long)kt * 32;
#pragma unroll
    for (int i = 0; i < 2; ++i) {
      int ch = wid * 2 + i;
      async_copy16(As + (long)(ch * 16 + srow) * 1536 + skk, &Ab[buf][ch * 512]);
      async_copy16(Bs + (long)(ch * 16 + srow) * 1536 + skk, &Bb[buf][ch * 512]);
    }
  };

  f32x4 acc[4][4] = {};
  stage(0, 0);
  __syncthreads();
  int buf = 0;
  const int wr = wid >> 1, wc = wid & 1;
  const int fr = lane & 15, fq = lane >> 4;
  for (int kt = 0; kt < 24; ++kt) {
    if (kt + 1 < 24) stage(buf ^ 1, kt + 1);
    const unsigned short* Ap = &Ab[buf][(wr * 64 + fr) * 32 + fq * 8];
    const unsigned short* Bp = &Bb[buf][(wc * 64 + fr) * 32 + fq * 8];
    bf16x8 af[4], bfv[4];
#pragma unroll
    for (int mi = 0; mi < 4; ++mi) af[mi] = *(const bf16x8*)(Ap + mi * 16 * 32);
#pragma unroll
    for (int ni = 0; ni < 4; ++ni) bfv[ni] = *(const bf16x8*)(Bp + ni * 16 * 32);
#pragma unroll
    for (int mi = 0; mi < 4; ++mi)
#pragma unroll
      for (int ni = 0; ni < 4; ++ni)
        acc[mi][ni] = __builtin_amdgcn_mfma_f32_16x16x32_bf16(af[mi], bfv[ni], acc[mi][ni], 0, 0, 0);
    __syncthreads();
    buf ^= 1;
  }

  float* C = attn + (long)bz * 1024 * 1024;
  const unsigned short* rvec = VTe + (long)256 * 16384 + (long)bz * 1024;
  const unsigned short* cvec = VTe + (long)257 * 16384 + (long)bz * 1024;
#pragma unroll
  for (int mi = 0; mi < 4; ++mi)
#pragma unroll
    for (int ni = 0; ni < 4; ++ni) {
      const long m = (long)bx * 128 + wr * 64 + mi * 16 + fq * 4;
      const long n = (long)by * 128 + wc * 64 + ni * 16 + fr;
      const float cB = bf2f(cvec[n]);
      f32x4 v = acc[mi][ni];
#pragma unroll
      for (int r = 0; r < 4; ++r) {
        const float rA = bf2f(rvec[m + r]);
        C[(m + r) * 1024 + n] = (v[r] + rA + cB) * INV_TEMP;
      }
    }
}

// ============ VT_ext: [384][16384] = WvTe * emb^T + bias_v(row) ============
__global__ __launch_bounds__(256) void gemm_vt(
    const unsigned short* __restrict__ WvTe,
    const unsigned short* __restrict__ QKE,   // emb view at +768, ld 1536
    const float* __restrict__ bias_v,
    unsigned short* __restrict__ VTe) {
  __shared__ unsigned short Ab[2][128 * 32];
  __shared__ unsigned short Bb[2][128 * 32];
  const int tid = threadIdx.x, wid = tid >> 6, lane = tid & 63;
  const unsigned short* A = WvTe + (long)blockIdx.x * 128 * 768;
  const unsigned short* BT = QKE + 768 + (long)blockIdx.y * 128 * 1536;
  const int srow = lane >> 2;
  const int skk = (lane & 3) * 8;

  auto stage = [&](int buf, int kt) {
    const unsigned short* As = A + (long)kt * 32;
    const unsigned short* Bs = BT + (long)kt * 32;
#pragma unroll
    for (int i = 0; i < 2; ++i) {
      int ch = wid * 2 + i;
      async_copy16(As + (long)(ch * 16 + srow) * 768 + skk, &Ab[buf][ch * 512]);
      async_copy16(Bs + (long)(ch * 16 + srow) * 1536 + skk, &Bb[buf][ch * 512]);
    }
  };

  f32x4 acc[4][4] = {};
  stage(0, 0);
  __syncthreads();
  int buf = 0;
  const int wr = wid >> 1, wc = wid & 1;
  const int fr = lane & 15, fq = lane >> 4;
  for (int kt = 0; kt < 24; ++kt) {
    if (kt + 1 < 24) stage(buf ^ 1, kt + 1);
    const unsigned short* Ap = &Ab[buf][(wr * 64 + fr) * 32 + fq * 8];
    const unsigned short* Bp = &Bb[buf][(wc * 64 + fr) * 32 + fq * 8];
    bf16x8 af[4], bfv[4];
#pragma unroll
    for (int mi = 0; mi < 4; ++mi) af[mi] = *(const bf16x8*)(Ap + mi * 16 * 32);
#pragma unroll
    for (int ni = 0; ni < 4; ++ni) bfv[ni] = *(const bf16x8*)(Bp + ni * 16 * 32);
#pragma unroll
    for (int mi = 0; mi < 4; ++mi)
#pragma unroll
      for (int ni = 0; ni < 4; ++ni)
        acc[mi][ni] = __builtin_amdgcn_mfma_f32_16x16x32_bf16(af[mi], bfv[ni], acc[mi][ni], 0, 0, 0);
    __syncthreads();
    buf ^= 1;
  }
#pragma unroll
  for (int mi = 0; mi < 4; ++mi)
#pragma unroll
    for (int ni = 0; ni < 4; ++ni) {
      const long m = (long)blockIdx.x * 128 + wr * 64 + mi * 16 + fq * 4;
      const long n = (long)blockIdx.y * 128 + wc * 64 + ni * 16 + fr;
      f32x4 v = acc[mi][ni];
#pragma unroll
      for (int r = 0; r < 4; ++r)
        VTe[(m + r) * 16384 + n] = f2bf(v[r] + bias_v[m + r]);
    }
}

// ---------------- masked row softmax + bf16 copy ----------------
__global__ __launch_bounds__(256) void softmax_rows(float* __restrict__ attn,
                                                    const int* __restrict__ mask,
                                                    unsigned short* __restrict__ attn_bf) {
  const int row = blockIdx.x;
  const int b = row >> 10;
  float* p = attn + (long)row * 1024;
  const int tid = threadIdx.x, lane = tid & 63, wid = tid >> 6;
  float4 v = ((const float4*)p)[tid];
  int4 mk = ((const int4*)(mask + b * 1024))[tid];
  v.x = mk.x ? v.x : -1e9f;
  v.y = mk.y ? v.y : -1e9f;
  v.z = mk.z ? v.z : -1e9f;
  v.w = mk.w ? v.w : -1e9f;
  float mx = fmaxf(fmaxf(v.x, v.y), fmaxf(v.z, v.w));
#pragma unroll
  for (int off = 32; off; off >>= 1) mx = fmaxf(mx, __shfl_xor(mx, off));
  __shared__ float red[4];
  if (lane == 0) red[wid] = mx;
  __syncthreads();
  mx = fmaxf(fmaxf(red[0], red[1]), fmaxf(red[2], red[3]));
  float e0 = __expf(v.x - mx), e1 = __expf(v.y - mx);
  float e2 = __expf(v.z - mx), e3 = __expf(v.w - mx);
  float s = e0 + e1 + e2 + e3;
#pragma unroll
  for (int off = 32; off; off >>= 1) s += __shfl_xor(s, off);
  __shared__ float red2[4];
  if (lane == 0) red2[wid] = s;
  __syncthreads();
  s = red2[0] + red2[1] + red2[2] + red2[3];
  const float inv = 1.0f / s;
  float4 o;
  o.x = e0 * inv; o.y = e1 * inv; o.z = e2 * inv; o.w = e3 * inv;
  ((float4*)p)[tid] = o;
  u16x4 ob;
  ob[0] = f2bf(o.x); ob[1] = f2bf(o.y); ob[2] = f2bf(o.z); ob[3] = f2bf(o.w);
  *(u16x4*)(attn_bf + (long)row * 1024 + tid * 4) = ob;
}

// ======== PV: 128x64 tiles, 512 blocks ========
__global__ __launch_bounds__(256) void gemm_pv(
    const unsigned short* __restrict__ attnbf,
    const unsigned short* __restrict__ VTe,
    float* __restrict__ out) {
  __shared__ unsigned short Ab[2][128 * 32];
  __shared__ unsigned short Bb[2][64 * 32];
  const int tid = threadIdx.x, wid = tid >> 6, lane = tid & 63;
  const int bz = blockIdx.z;
  const unsigned short* A = attnbf + (long)bz * 1024 * 1024 + (long)blockIdx.x * 128 * 1024;
  const unsigned short* BT = VTe + (long)bz * 1024 + (long)blockIdx.y * 64 * 16384;
  const int srow = lane >> 2;
  const int skk = (lane & 3) * 8;

  auto stage = [&](int buf, int kt) {
    const unsigned short* As = A + (long)kt * 32;
    const unsigned short* Bs = BT + (long)kt * 32;
#pragma unroll
    for (int i = 0; i < 2; ++i) {
      int ch = wid * 2 + i;
      async_copy16(As + (long)(ch * 16 + srow) * 1024 + skk, &Ab[buf][ch * 512]);
    }
    async_copy16(Bs + (long)(wid * 16 + srow) * 16384 + skk, &Bb[buf][wid * 512]);
  };

  f32x4 acc[4][2] = {};
  stage(0, 0);
  __syncthreads();
  int buf = 0;
  const int wr = wid >> 1, wc = wid & 1;
  const int fr = lane & 15, fq = lane >> 4;
  for (int kt = 0; kt < 32; ++kt) {
    if (kt + 1 < 32) stage(buf ^ 1, kt + 1);
    const unsigned short* Ap = &Ab[buf][(wr * 64 + fr) * 32 + fq * 8];
    const unsigned short* Bp = &Bb[buf][(wc * 32 + fr) * 32 + fq * 8];
    bf16x8 af[4], bfv[2];
#pragma unroll
    for (int mi = 0; mi < 4; ++mi) af[mi] = *(const bf16x8*)(Ap + mi * 16 * 32);
#pragma unroll
    for (int ni = 0; ni < 2; ++ni) bfv[ni] = *(const bf16x8*)(Bp + ni * 16 * 32);
#pragma unroll
    for (int mi = 0; mi < 4; ++mi)
#pragma unroll
      for (int ni = 0; ni < 2; ++ni)
        acc[mi][ni] = __builtin_amdgcn_mfma_f32_16x16x32_bf16(af[mi], bfv[ni], acc[mi][ni], 0, 0, 0);
    __syncthreads();
    buf ^= 1;
  }

  float* C = out + (long)bz * 1024 * 256;
  const long m0 = (long)blockIdx.x * 128 + wr * 64;
  const long n0 = (long)blockIdx.y * 64 + wc * 32;
#pragma unroll
  for (int mi = 0; mi < 4; ++mi)
#pragma unroll
    for (int ni = 0; ni < 2; ++ni) {
      const long m = m0 + mi * 16 + fq * 4;
      const long n = n0 + ni * 16 + fr;
      f32x4 v = acc[mi][ni];
#pragma unroll
      for (int r = 0; r < 4; ++r) C[(m + r) * 256 + n] = v[r];
    }
}

// ---------------- launch ----------------
extern "C" void kernel_launch(void* const* d_in, const int* in_sizes, int n_in,
                              void* d_out, int out_size, void* d_ws, size_t ws_size,
                              hipStream_t stream) {
  const float* emb = (const float*)d_in[0];
  const int* mask = (const int*)d_in[1];
  const int* isq = (const int*)d_in[2];
  const float* qWq = (const float*)d_in[3];  const float* qbq = (const float*)d_in[4];
  const float* qWk = (const float*)d_in[5];  const float* qbk = (const float*)d_in[6];
  const float* qWv = (const float*)d_in[7];  const float* qbv = (const float*)d_in[8];
  const float* dWq = (const float*)d_in[9];  const float* dbq = (const float*)d_in[10];
  const float* dWk = (const float*)d_in[11]; const float* dbk = (const float*)d_in[12];
  const float* dWv = (const float*)d_in[13]; const float* dbv = (const float*)d_in[14];

  char* ws = (char*)d_ws;
  unsigned short* QKE    = (unsigned short*)ws;  ws += (size_t)16384 * 1536 * 2;   // 50.3 MB: T | emb
  unsigned short* Wq_bf  = (unsigned short*)ws;  ws += (size_t)768 * 768 * 2;
  unsigned short* Wk_bf  = (unsigned short*)ws;  ws += (size_t)768 * 768 * 2;
  unsigned short* WvTe   = (unsigned short*)ws;  ws += (size_t)384 * 768 * 2;
  unsigned short* Gt     = (unsigned short*)ws;  ws += (size_t)768 * 768 * 2;
  float*          bias_v = (float*)ws;           ws += (size_t)384 * 4;
  unsigned short* VTe    = (unsigned short*)ws;  ws += (size_t)384 * 16384 * 2;    // 12.6 MB
  unsigned short* attnbf = (unsigned short*)ws;  ws += (size_t)16 * 1024 * 1024 * 2;

  float* out = (float*)d_out;                    // [16,1024,256]
  float* attn = out + (size_t)16 * 1024 * 256;   // [16,1024,1024]

  hipLaunchKernelGGL(pack_emb, dim3(6144), dim3(256), 0, stream, emb, QKE);
  hipLaunchKernelGGL(pack_sel, dim3(1345), dim3(256), 0, stream, isq,
                     qWq, qWk, qWv, qbv, dWq, dWk, dWv, dbv, Wq_bf, Wk_bf, WvTe, bias_v);
  // Gt = Wk * Wq^T  [768][768]
  hipLaunchKernelGGL(gemm_g, dim3(12, 12), dim3(256), 0, stream, Wk_bf, Wq_bf, Gt);
  // WvTe rows 256/257 = u,v;  bias_v[256]=c
  hipLaunchKernelGGL(uvc_fast, dim3(1537), dim3(256), 0, stream, isq,
                     qWq, qbq, qWk, qbk, dWq, dbq, dWk, dbk, WvTe, bias_v);
  // T (QKE cols 0..767) = emb * Gt^T — 2-phase 128^2, 768 blocks XCD-chunked
  hipLaunchKernelGGL(tproj2, dim3(768), dim3(256), 0, stream, QKE, Gt);
  // VTe = WvTe * emb^T + bias_v
  hipLaunchKernelGGL(gemm_vt, dim3(3, 128), dim3(256), 0, stream,
                     WvTe, QKE, bias_v, VTe);
  // logits = (T*emb^T + rvec + cvec) * INV_TEMP — 2-phase 128^2, 1024 blocks (1 round @4/CU)
  hipLaunchKernelGGL(logits2, dim3(1024), dim3(256), 0, stream, QKE, VTe, attn);
  hipLaunchKernelGGL(softmax_rows, dim3(16384), dim3(256), 0, stream, attn, mask, attnbf);
  hipLaunchKernelGGL(gemm_pv, dim3(8, 4, 16), dim3(256), 0, stream, attnbf, VTe, out);
}

// Round 12
// 163.932 us; speedup vs baseline: 1.1387x; 1.1387x over previous
//
#include <hip/hip_runtime.h>
#include <hip/hip_bf16.h>

// Problem constants: B=16, S=1024, D=768, DOUT=256
static constexpr float INV_TEMP = 0.03608439182435161f; // 1/sqrt(768)

typedef __attribute__((ext_vector_type(8))) short bf16x8;
typedef __attribute__((ext_vector_type(4))) float f32x4;
typedef __attribute__((ext_vector_type(8))) unsigned short u16x8;
typedef __attribute__((ext_vector_type(4))) unsigned short u16x4;

__device__ __forceinline__ unsigned short f2bf(float f) {
  unsigned u = __float_as_uint(f);
  u += 0x7fffu + ((u >> 16) & 1u);
  return (unsigned short)(u >> 16);
}

__device__ __forceinline__ void async_copy16(const void* g, void* lds) {
  __builtin_amdgcn_global_load_lds(
      (const __attribute__((address_space(1))) unsigned int*)g,
      (__attribute__((address_space(3))) unsigned int*)lds, 16, 0, 0);
}

// ---------------- pack kernels ----------------
__global__ __launch_bounds__(256) void pack_emb(const float* __restrict__ src,
                                                unsigned short* __restrict__ dst) {
  long i = ((long)blockIdx.x * 256 + threadIdx.x) * 8;
  float4 a = *(const float4*)(src + i);
  float4 b = *(const float4*)(src + i + 4);
  u16x8 v;
  v[0] = f2bf(a.x); v[1] = f2bf(a.y); v[2] = f2bf(a.z); v[3] = f2bf(a.w);
  v[4] = f2bf(b.x); v[5] = f2bf(b.y); v[6] = f2bf(b.z); v[7] = f2bf(b.w);
  *(u16x8*)(dst + i) = v;
}

__global__ __launch_bounds__(256) void pack_w(
    const int* __restrict__ isq_p,
    const float* qWq, const float* qbq, const float* qWk, const float* qbk,
    const float* qWv, const float* qbv,
    const float* dWq, const float* dbq, const float* dWk, const float* dbk,
    const float* dWv, const float* dbv,
    unsigned short* __restrict__ WT, float* __restrict__ bias) {
  const int n = blockIdx.x;  // 0..1791
  const int isq = *isq_p;
  const float* W; const float* bsrc; int col, srcN;
  if (n < 768)       { W = isq ? qWq : dWq; bsrc = isq ? qbq : dbq; col = n;        srcN = 768; }
  else if (n < 1536) { W = isq ? qWk : dWk; bsrc = isq ? qbk : dbk; col = n - 768;  srcN = 768; }
  else               { W = isq ? qWv : dWv; bsrc = isq ? qbv : dbv; col = n - 1536; srcN = 256; }
#pragma unroll
  for (int i = 0; i < 3; ++i) {
    int d = threadIdx.x + i * 256;
    WT[(long)n * 768 + d] = f2bf(W[(long)d * srcN + col]);
  }
  if (threadIdx.x == 0) bias[n] = bsrc[col];
}

// ============ shared 256x256 8-phase K-loop (T2+T3+T4+T5) ============
// LDS: [buf(2)][region: A0,A1,B0,B1][256 x 32] bf16 = 128 KiB.
__device__ __forceinline__ void k_loop_256(
    const unsigned short* __restrict__ Apan, long lda,
    const unsigned short* __restrict__ Bpan, long ldb,
    int nk, unsigned short* smem, f32x4 (&acc)[8][4]) {
  const int tid = threadIdx.x;
  const int wid = tid >> 6, lane = tid & 63;
  const int wr = wid >> 2, wc = wid & 3;   // 2 (M) x 4 (N) wave grid
  const int fr = lane & 15, fq = lane >> 4;

  auto stage = [&](int tile, int mat, int ks, int buf) {
    const unsigned short* g = (mat ? Bpan : Apan) + (long)tile * 64 + ks * 32;
    const long ld = mat ? ldb : lda;
    unsigned short* d = smem + (((buf << 2) | (mat << 1) | ks) << 13);
#pragma unroll
    for (int i = 0; i < 2; ++i) {
      const int e = (tid + i * 512) * 8;
      const int row = e >> 5;
      const int sl = (e >> 3) & 3;
      const int ss = sl ^ ((row >> 1) & 3);
      async_copy16(g + (long)row * ld + ss * 8, d + e);
    }
  };

  const int fro = fr * 32 + ((fq ^ ((fr >> 1) & 3)) << 3);
  const int awo = fro + (wr * 128) * 32;
  const int bwo = fro + (wc * 64) * 32;

  stage(0, 0, 0, 0); stage(0, 1, 0, 0); stage(0, 0, 1, 0); stage(0, 1, 1, 0);
  if (nk > 1) {
    stage(1, 0, 0, 1); stage(1, 1, 1, 1);
    asm volatile("s_waitcnt vmcnt(4)" ::: "memory");
  } else {
    asm volatile("s_waitcnt vmcnt(0)" ::: "memory");
  }
  __builtin_amdgcn_sched_barrier(0);
  __builtin_amdgcn_s_barrier();

  for (int t = 0; t < nk; ++t) {
    const int p = t & 1;
    const unsigned short* A0 = smem + (((p << 2) | 0) << 13);
    const unsigned short* A1 = smem + (((p << 2) | 1) << 13);
    const unsigned short* B0 = smem + (((p << 2) | 2) << 13);
    const unsigned short* B1 = smem + (((p << 2) | 3) << 13);
    bf16x8 a[4], b[4];

    // phase 0: ksub0, m0..3
#pragma unroll
    for (int m = 0; m < 4; ++m) a[m] = *(const bf16x8*)(A0 + awo + m * 512);
#pragma unroll
    for (int n = 0; n < 4; ++n) b[n] = *(const bf16x8*)(B0 + bwo + n * 512);
    if (t + 1 < nk) stage(t + 1, 0, 1, (t + 1) & 1);
    __builtin_amdgcn_s_barrier();
    asm volatile("s_waitcnt lgkmcnt(0)");
    __builtin_amdgcn_sched_barrier(0);
    __builtin_amdgcn_s_setprio(1);
#pragma unroll
    for (int m = 0; m < 4; ++m)
#pragma unroll
      for (int n = 0; n < 4; ++n)
        acc[m][n] = __builtin_amdgcn_mfma_f32_16x16x32_bf16(a[m], b[n], acc[m][n], 0, 0, 0);
    __builtin_amdgcn_s_setprio(0);
    __builtin_amdgcn_sched_barrier(0);
    __builtin_amdgcn_s_barrier();

    // phase 1: ksub0, m4..7
#pragma unroll
    for (int m = 0; m < 4; ++m) a[m] = *(const bf16x8*)(A0 + awo + (4 + m) * 512);
    if (t + 1 < nk) stage(t + 1, 1, 0, (t + 1) & 1);
    __builtin_amdgcn_s_barrier();
    asm volatile("s_waitcnt lgkmcnt(0)");
    __builtin_amdgcn_sched_barrier(0);
    __builtin_amdgcn_s_setprio(1);
#pragma unroll
    for (int m = 0; m < 4; ++m)
#pragma unroll
      for (int n = 0; n < 4; ++n)
        acc[4 + m][n] = __builtin_amdgcn_mfma_f32_16x16x32_bf16(a[m], b[n], acc[4 + m][n], 0, 0, 0);
    __builtin_amdgcn_s_setprio(0);
    __builtin_amdgcn_sched_barrier(0);
    __builtin_amdgcn_s_barrier();

    // phase 2: ksub1, m0..3
#pragma unroll
    for (int m = 0; m < 4; ++m) a[m] = *(const bf16x8*)(A1 + awo + m * 512);
#pragma unroll
    for (int n = 0; n < 4; ++n) b[n] = *(const bf16x8*)(B1 + bwo + n * 512);
    if (t + 2 < nk) stage(t + 2, 0, 0, p);
    __builtin_amdgcn_s_barrier();
    asm volatile("s_waitcnt lgkmcnt(0)");
    __builtin_amdgcn_sched_barrier(0);
    __builtin_amdgcn_s_setprio(1);
#pragma unroll
    for (int m = 0; m < 4; ++m)
#pragma unroll
      for (int n = 0; n < 4; ++n)
        acc[m][n] = __builtin_amdgcn_mfma_f32_16x16x32_bf16(a[m], b[n], acc[m][n], 0, 0, 0);
    __builtin_amdgcn_s_setprio(0);
    __builtin_amdgcn_sched_barrier(0);
    __builtin_amdgcn_s_barrier();

    // phase 3: ksub1, m4..7 + tile-end counted vmcnt
#pragma unroll
    for (int m = 0; m < 4; ++m) a[m] = *(const bf16x8*)(A1 + awo + (4 + m) * 512);
    if (t + 2 < nk) stage(t + 2, 1, 1, p);
    __builtin_amdgcn_s_barrier();
    asm volatile("s_waitcnt lgkmcnt(0)");
    __builtin_amdgcn_sched_barrier(0);
    __builtin_amdgcn_s_setprio(1);
#pragma unroll
    for (int m = 0; m < 4; ++m)
#pragma unroll
      for (int n = 0; n < 4; ++n)
        acc[4 + m][n] = __builtin_amdgcn_mfma_f32_16x16x32_bf16(a[m], b[n], acc[4 + m][n], 0, 0, 0);
    __builtin_amdgcn_s_setprio(0);
    if (t < nk - 2) {
      asm volatile("s_waitcnt vmcnt(4)" ::: "memory");
    } else if (t == nk - 2) {
      asm volatile("s_waitcnt vmcnt(0)" ::: "memory");
    }
    __builtin_amdgcn_sched_barrier(0);
    __builtin_amdgcn_s_barrier();
  }
}

// ============ merged projection: QK (384 jobs) + VT (64 jobs), XCD-chunked ============
// flat f in [0,448): k=f&7 (XCD), c=f>>3 in [0,56).
//   c<48 : QK job  xa = 8k+(c&7) in [0,64), yb = c>>3 in [0,6)
//   c>=48: VT job  v  = 8k+(c-48) in [0,64)
__global__ __launch_bounds__(512, 2) void proj256(
    const unsigned short* __restrict__ emb_bf,
    const unsigned short* __restrict__ WT,
    const float* __restrict__ bias,
    unsigned short* __restrict__ QK,
    unsigned short* __restrict__ VT) {
  extern __shared__ unsigned short smem[];
  const int f = blockIdx.x;
  const int kx = f & 7, c = f >> 3;
  const int isQK = c < 48;
  long xa, yb;
  const unsigned short* Apan;
  const unsigned short* Bpan;
  if (isQK) {
    xa = kx * 8 + (c & 7); yb = c >> 3;
    Apan = emb_bf + xa * 256 * 768;
    Bpan = WT + yb * 256 * 768;
  } else {
    xa = 0; yb = kx * 8 + (c - 48);
    Apan = WT + (long)1536 * 768;
    Bpan = emb_bf + yb * 256 * 768;
  }
  f32x4 acc[8][4];
#pragma unroll
  for (int m = 0; m < 8; ++m)
#pragma unroll
    for (int n = 0; n < 4; ++n) acc[m][n] = f32x4{0.f, 0.f, 0.f, 0.f};

  k_loop_256(Apan, 768, Bpan, 768, 12, smem, acc);

  const int wid = threadIdx.x >> 6, lane = threadIdx.x & 63;
  const int wr = wid >> 2, wc = wid & 3;
  const int fr = lane & 15, fq = lane >> 4;
  if (isQK) {
#pragma unroll
    for (int m = 0; m < 8; ++m)
#pragma unroll
      for (int n = 0; n < 4; ++n) {
        const long mm = xa * 256 + wr * 128 + m * 16 + fq * 4;
        const long nn = yb * 256 + wc * 64 + n * 16 + fr;
        const float bb = bias[nn];
        f32x4 v = acc[m][n];
#pragma unroll
        for (int r = 0; r < 4; ++r) QK[(mm + r) * 1536 + nn] = f2bf(v[r] + bb);
      }
  } else {
#pragma unroll
    for (int m = 0; m < 8; ++m)
#pragma unroll
      for (int n = 0; n < 4; ++n) {
        const long mm = wr * 128 + m * 16 + fq * 4;   // DOUT row 0..255
        const long nn = yb * 256 + wc * 64 + n * 16 + fr;
        f32x4 v = acc[m][n];
#pragma unroll
        for (int r = 0; r < 4; ++r)
          VT[(mm + r) * 16384 + nn] = f2bf(v[r] + bias[1536 + mm + r]);
      }
  }
}

// ============ logits: per-batch Q*K^T * invTemp, XCD-chunked by batch pair ============
// flat f in [0,256): k=f&7 (XCD), c=f>>3 in [0,32).
//   bz = 2k + (c>>4); inner = c&15; bx = inner&3; by = inner>>2.
__global__ __launch_bounds__(512, 2) void logits256(
    const unsigned short* __restrict__ QK, float* __restrict__ attn) {
  extern __shared__ unsigned short smem[];
  const int f = blockIdx.x;
  const int kx = f & 7, c = f >> 3;
  const int bz = 2 * kx + (c >> 4);
  const int inner = c & 15, bx = inner & 3, by = inner >> 2;
  const unsigned short* Apan = QK + (long)bz * 1024 * 1536 + (long)bx * 256 * 1536;
  const unsigned short* Bpan = QK + 768 + (long)bz * 1024 * 1536 + (long)by * 256 * 1536;
  f32x4 acc[8][4];
#pragma unroll
  for (int m = 0; m < 8; ++m)
#pragma unroll
    for (int n = 0; n < 4; ++n) acc[m][n] = f32x4{0.f, 0.f, 0.f, 0.f};

  k_loop_256(Apan, 1536, Bpan, 1536, 12, smem, acc);

  const int wid = threadIdx.x >> 6, lane = threadIdx.x & 63;
  const int wr = wid >> 2, wc = wid & 3;
  const int fr = lane & 15, fq = lane >> 4;
  float* C = attn + (long)bz * 1024 * 1024;
#pragma unroll
  for (int m = 0; m < 8; ++m)
#pragma unroll
    for (int n = 0; n < 4; ++n) {
      const long mm = (long)bx * 256 + wr * 128 + m * 16 + fq * 4;
      const long nn = (long)by * 256 + wc * 64 + n * 16 + fr;
      f32x4 v = acc[m][n];
#pragma unroll
      for (int r = 0; r < 4; ++r) C[(mm + r) * 1024 + nn] = v[r] * INV_TEMP;
    }
}

// ---------------- masked row softmax + bf16 copy ----------------
__global__ __launch_bounds__(256) void softmax_rows(float* __restrict__ attn,
                                                    const int* __restrict__ mask,
                                                    unsigned short* __restrict__ attn_bf) {
  const int row = blockIdx.x;
  const int b = row >> 10;
  float* p = attn + (long)row * 1024;
  const int tid = threadIdx.x, lane = tid & 63, wid = tid >> 6;
  float4 v = ((const float4*)p)[tid];
  int4 mk = ((const int4*)(mask + b * 1024))[tid];
  v.x = mk.x ? v.x : -1e9f;
  v.y = mk.y ? v.y : -1e9f;
  v.z = mk.z ? v.z : -1e9f;
  v.w = mk.w ? v.w : -1e9f;
  float mx = fmaxf(fmaxf(v.x, v.y), fmaxf(v.z, v.w));
#pragma unroll
  for (int off = 32; off; off >>= 1) mx = fmaxf(mx, __shfl_xor(mx, off));
  __shared__ float red[4];
  if (lane == 0) red[wid] = mx;
  __syncthreads();
  mx = fmaxf(fmaxf(red[0], red[1]), fmaxf(red[2], red[3]));
  float e0 = __expf(v.x - mx), e1 = __expf(v.y - mx);
  float e2 = __expf(v.z - mx), e3 = __expf(v.w - mx);
  float s = e0 + e1 + e2 + e3;
#pragma unroll
  for (int off = 32; off; off >>= 1) s += __shfl_xor(s, off);
  __shared__ float red2[4];
  if (lane == 0) red2[wid] = s;
  __syncthreads();
  s = red2[0] + red2[1] + red2[2] + red2[3];
  const float inv = 1.0f / s;
  float4 o;
  o.x = e0 * inv; o.y = e1 * inv; o.z = e2 * inv; o.w = e3 * inv;
  ((float4*)p)[tid] = o;
  u16x4 ob;
  ob[0] = f2bf(o.x); ob[1] = f2bf(o.y); ob[2] = f2bf(o.z); ob[3] = f2bf(o.w);
  *(u16x4*)(attn_bf + (long)row * 1024 + tid * 4) = ob;
}

// ======== PV: 128x64 tiles, 512 blocks ========
__global__ __launch_bounds__(256) void gemm_pv(
    const unsigned short* __restrict__ attnbf,   // [16][1024][1024]
    const unsigned short* __restrict__ VT,       // [256][16384]
    float* __restrict__ out) {                   // [16][1024][256]
  __shared__ unsigned short Ab[2][128 * 32];
  __shared__ unsigned short Bb[2][64 * 32];
  const int tid = threadIdx.x, wid = tid >> 6, lane = tid & 63;
  const int bz = blockIdx.z;
  const unsigned short* A = attnbf + (long)bz * 1024 * 1024 + (long)blockIdx.x * 128 * 1024;
  const unsigned short* BT = VT + (long)bz * 1024 + (long)blockIdx.y * 64 * 16384;
  const int srow = lane >> 2;
  const int skk = (lane & 3) * 8;

  auto stage = [&](int buf, int kt) {
    const unsigned short* As = A + (long)kt * 32;
    const unsigned short* Bs = BT + (long)kt * 32;
#pragma unroll
    for (int i = 0; i < 2; ++i) {
      int c = wid * 2 + i;
      async_copy16(As + (long)(c * 16 + srow) * 1024 + skk, &Ab[buf][c * 512]);
    }
    async_copy16(Bs + (long)(wid * 16 + srow) * 16384 + skk, &Bb[buf][wid * 512]);
  };

  f32x4 acc[4][2] = {};
  stage(0, 0);
  __syncthreads();
  int buf = 0;
  const int wr = wid >> 1, wc = wid & 1;
  const int fr = lane & 15, fq = lane >> 4;
  for (int kt = 0; kt < 32; ++kt) {
    if (kt + 1 < 32) stage(buf ^ 1, kt + 1);
    const unsigned short* Ap = &Ab[buf][(wr * 64 + fr) * 32 + fq * 8];
    const unsigned short* Bp = &Bb[buf][(wc * 32 + fr) * 32 + fq * 8];
    bf16x8 af[4], bfv[2];
#pragma unroll
    for (int mi = 0; mi < 4; ++mi) af[mi] = *(const bf16x8*)(Ap + mi * 16 * 32);
#pragma unroll
    for (int ni = 0; ni < 2; ++ni) bfv[ni] = *(const bf16x8*)(Bp + ni * 16 * 32);
#pragma unroll
    for (int mi = 0; mi < 4; ++mi)
#pragma unroll
      for (int ni = 0; ni < 2; ++ni)
        acc[mi][ni] = __builtin_amdgcn_mfma_f32_16x16x32_bf16(af[mi], bfv[ni], acc[mi][ni], 0, 0, 0);
    __syncthreads();
    buf ^= 1;
  }

  float* C = out + (long)bz * 1024 * 256;
  const long m0 = (long)blockIdx.x * 128 + wr * 64;
  const long n0 = (long)blockIdx.y * 64 + wc * 32;
#pragma unroll
  for (int mi = 0; mi < 4; ++mi)
#pragma unroll
    for (int ni = 0; ni < 2; ++ni) {
      const long m = m0 + mi * 16 + fq * 4;
      const long n = n0 + ni * 16 + fr;
      f32x4 v = acc[mi][ni];
#pragma unroll
      for (int r = 0; r < 4; ++r) C[(m + r) * 256 + n] = v[r];
    }
}

// ---------------- launch ----------------
extern "C" void kernel_launch(void* const* d_in, const int* in_sizes, int n_in,
                              void* d_out, int out_size, void* d_ws, size_t ws_size,
                              hipStream_t stream) {
  const float* emb = (const float*)d_in[0];
  const int* mask = (const int*)d_in[1];
  const int* isq = (const int*)d_in[2];
  const float* qWq = (const float*)d_in[3];  const float* qbq = (const float*)d_in[4];
  const float* qWk = (const float*)d_in[5];  const float* qbk = (const float*)d_in[6];
  const float* qWv = (const float*)d_in[7];  const float* qbv = (const float*)d_in[8];
  const float* dWq = (const float*)d_in[9];  const float* dbq = (const float*)d_in[10];
  const float* dWk = (const float*)d_in[11]; const float* dbk = (const float*)d_in[12];
  const float* dWv = (const float*)d_in[13]; const float* dbv = (const float*)d_in[14];

  char* ws = (char*)d_ws;
  unsigned short* emb_bf = (unsigned short*)ws;  ws += (size_t)16384 * 768 * 2;
  unsigned short* WT     = (unsigned short*)ws;  ws += (size_t)1792 * 768 * 2;
  float*          bias   = (float*)ws;           ws += (size_t)1792 * 4;
  unsigned short* QK     = (unsigned short*)ws;  ws += (size_t)16384 * 1536 * 2;
  unsigned short* VT     = (unsigned short*)ws;  ws += (size_t)256 * 16384 * 2;
  unsigned short* attnbf = (unsigned short*)ws;  ws += (size_t)16 * 1024 * 1024 * 2;

  float* out = (float*)d_out;                    // [16,1024,256]
  float* attn = out + (size_t)16 * 1024 * 256;   // [16,1024,1024]

  (void)hipFuncSetAttribute((const void*)&proj256,
                            hipFuncAttributeMaxDynamicSharedMemorySize, 131072);
  (void)hipFuncSetAttribute((const void*)&logits256,
                            hipFuncAttributeMaxDynamicSharedMemorySize, 131072);

  hipLaunchKernelGGL(pack_emb, dim3(6144), dim3(256), 0, stream, emb, emb_bf);
  hipLaunchKernelGGL(pack_w, dim3(1792), dim3(256), 0, stream, isq,
                     qWq, qbq, qWk, qbk, qWv, qbv, dWq, dbq, dWk, dbk, dWv, dbv, WT, bias);
  // merged Q|K projection + V^T projection, XCD-chunked block order
  hipLaunchKernelGGL(proj256, dim3(448), dim3(512), 131072, stream,
                     emb_bf, WT, bias, QK, VT);
  // logits: per batch [1024,1024] = Q_b * K_b^T * invTemp, XCD-chunked by batch pair
  hipLaunchKernelGGL(logits256, dim3(256), dim3(512), 131072, stream, QK, attn);
  // masked row softmax in-place + bf16 copy
  hipLaunchKernelGGL(softmax_rows, dim3(16384), dim3(256), 0, stream, attn, mask, attnbf);
  // out: per batch [1024,256] = attn_bf * V_b^T
  hipLaunchKernelGGL(gemm_pv, dim3(8, 4, 16), dim3(256), 0, stream, attnbf, VT, out);
}

// Round 13
// 157.271 us; speedup vs baseline: 1.1870x; 1.0424x over previous
//
#include <hip/hip_runtime.h>
#include <hip/hip_bf16.h>

// Problem constants: B=16, S=1024, D=768, DOUT=256
static constexpr float INV_TEMP = 0.03608439182435161f; // 1/sqrt(768)

typedef __attribute__((ext_vector_type(8))) short bf16x8;
typedef __attribute__((ext_vector_type(4))) float f32x4;
typedef __attribute__((ext_vector_type(8))) unsigned short u16x8;
typedef __attribute__((ext_vector_type(4))) unsigned short u16x4;

__device__ __forceinline__ unsigned short f2bf(float f) {
  unsigned u = __float_as_uint(f);
  u += 0x7fffu + ((u >> 16) & 1u);
  return (unsigned short)(u >> 16);
}

__device__ __forceinline__ void async_copy16(const void* g, void* lds) {
  __builtin_amdgcn_global_load_lds(
      (const __attribute__((address_space(1))) unsigned int*)g,
      (__attribute__((address_space(3))) unsigned int*)lds, 16, 0, 0);
}

// ---------------- pack kernels ----------------
// XCD-chunked: XCD k (f&7) packs emb rows [2048k, 2048k+2048) so its L2 holds
// exactly the A-panels proj256's XCD-k jobs will read.
__global__ __launch_bounds__(256) void pack_emb(const float* __restrict__ src,
                                                unsigned short* __restrict__ dst) {
  const int f = blockIdx.x;            // 6144 = 8 * 768
  const int kx = f & 7, c = f >> 3;    // c in [0,768)
  long i = (long)kx * 1572864 + (long)c * 2048 + (long)threadIdx.x * 8;  // 1572864 = 2048*768
  float4 a = *(const float4*)(src + i);
  float4 b = *(const float4*)(src + i + 4);
  u16x8 v;
  v[0] = f2bf(a.x); v[1] = f2bf(a.y); v[2] = f2bf(a.z); v[3] = f2bf(a.w);
  v[4] = f2bf(b.x); v[5] = f2bf(b.y); v[6] = f2bf(b.z); v[7] = f2bf(b.w);
  *(u16x8*)(dst + i) = v;
}

__global__ __launch_bounds__(256) void pack_w(
    const int* __restrict__ isq_p,
    const float* qWq, const float* qbq, const float* qWk, const float* qbk,
    const float* qWv, const float* qbv,
    const float* dWq, const float* dbq, const float* dWk, const float* dbk,
    const float* dWv, const float* dbv,
    unsigned short* __restrict__ WT, float* __restrict__ bias) {
  const int n = blockIdx.x;  // 0..1791
  const int isq = *isq_p;
  const float* W; const float* bsrc; int col, srcN;
  if (n < 768)       { W = isq ? qWq : dWq; bsrc = isq ? qbq : dbq; col = n;        srcN = 768; }
  else if (n < 1536) { W = isq ? qWk : dWk; bsrc = isq ? qbk : dbk; col = n - 768;  srcN = 768; }
  else               { W = isq ? qWv : dWv; bsrc = isq ? qbv : dbv; col = n - 1536; srcN = 256; }
#pragma unroll
  for (int i = 0; i < 3; ++i) {
    int d = threadIdx.x + i * 256;
    WT[(long)n * 768 + d] = f2bf(W[(long)d * srcN + col]);
  }
  if (threadIdx.x == 0) bias[n] = bsrc[col];
}

// ============ shared 256x256 8-phase K-loop (T2+T3+T4+T5) ============
// LDS: [buf(2)][region: A0,A1,B0,B1][256 x 32] bf16 = 128 KiB.
__device__ __forceinline__ void k_loop_256(
    const unsigned short* __restrict__ Apan, long lda,
    const unsigned short* __restrict__ Bpan, long ldb,
    int nk, unsigned short* smem, f32x4 (&acc)[8][4]) {
  const int tid = threadIdx.x;
  const int wid = tid >> 6, lane = tid & 63;
  const int wr = wid >> 2, wc = wid & 3;   // 2 (M) x 4 (N) wave grid
  const int fr = lane & 15, fq = lane >> 4;

  auto stage = [&](int tile, int mat, int ks, int buf) {
    const unsigned short* g = (mat ? Bpan : Apan) + (long)tile * 64 + ks * 32;
    const long ld = mat ? ldb : lda;
    unsigned short* d = smem + (((buf << 2) | (mat << 1) | ks) << 13);
#pragma unroll
    for (int i = 0; i < 2; ++i) {
      const int e = (tid + i * 512) * 8;
      const int row = e >> 5;
      const int sl = (e >> 3) & 3;
      const int ss = sl ^ ((row >> 1) & 3);
      async_copy16(g + (long)row * ld + ss * 8, d + e);
    }
  };

  const int fro = fr * 32 + ((fq ^ ((fr >> 1) & 3)) << 3);
  const int awo = fro + (wr * 128) * 32;
  const int bwo = fro + (wc * 64) * 32;

  stage(0, 0, 0, 0); stage(0, 1, 0, 0); stage(0, 0, 1, 0); stage(0, 1, 1, 0);
  if (nk > 1) {
    stage(1, 0, 0, 1); stage(1, 1, 1, 1);
    asm volatile("s_waitcnt vmcnt(4)" ::: "memory");
  } else {
    asm volatile("s_waitcnt vmcnt(0)" ::: "memory");
  }
  __builtin_amdgcn_sched_barrier(0);
  __builtin_amdgcn_s_barrier();

  for (int t = 0; t < nk; ++t) {
    const int p = t & 1;
    const unsigned short* A0 = smem + (((p << 2) | 0) << 13);
    const unsigned short* A1 = smem + (((p << 2) | 1) << 13);
    const unsigned short* B0 = smem + (((p << 2) | 2) << 13);
    const unsigned short* B1 = smem + (((p << 2) | 3) << 13);
    bf16x8 a[4], b[4];

    // phase 0: ksub0, m0..3
#pragma unroll
    for (int m = 0; m < 4; ++m) a[m] = *(const bf16x8*)(A0 + awo + m * 512);
#pragma unroll
    for (int n = 0; n < 4; ++n) b[n] = *(const bf16x8*)(B0 + bwo + n * 512);
    if (t + 1 < nk) stage(t + 1, 0, 1, (t + 1) & 1);
    __builtin_amdgcn_s_barrier();
    asm volatile("s_waitcnt lgkmcnt(0)");
    __builtin_amdgcn_sched_barrier(0);
    __builtin_amdgcn_s_setprio(1);
#pragma unroll
    for (int m = 0; m < 4; ++m)
#pragma unroll
      for (int n = 0; n < 4; ++n)
        acc[m][n] = __builtin_amdgcn_mfma_f32_16x16x32_bf16(a[m], b[n], acc[m][n], 0, 0, 0);
    __builtin_amdgcn_s_setprio(0);
    __builtin_amdgcn_sched_barrier(0);
    __builtin_amdgcn_s_barrier();

    // phase 1: ksub0, m4..7
#pragma unroll
    for (int m = 0; m < 4; ++m) a[m] = *(const bf16x8*)(A0 + awo + (4 + m) * 512);
    if (t + 1 < nk) stage(t + 1, 1, 0, (t + 1) & 1);
    __builtin_amdgcn_s_barrier();
    asm volatile("s_waitcnt lgkmcnt(0)");
    __builtin_amdgcn_sched_barrier(0);
    __builtin_amdgcn_s_setprio(1);
#pragma unroll
    for (int m = 0; m < 4; ++m)
#pragma unroll
      for (int n = 0; n < 4; ++n)
        acc[4 + m][n] = __builtin_amdgcn_mfma_f32_16x16x32_bf16(a[m], b[n], acc[4 + m][n], 0, 0, 0);
    __builtin_amdgcn_s_setprio(0);
    __builtin_amdgcn_sched_barrier(0);
    __builtin_amdgcn_s_barrier();

    // phase 2: ksub1, m0..3
#pragma unroll
    for (int m = 0; m < 4; ++m) a[m] = *(const bf16x8*)(A1 + awo + m * 512);
#pragma unroll
    for (int n = 0; n < 4; ++n) b[n] = *(const bf16x8*)(B1 + bwo + n * 512);
    if (t + 2 < nk) stage(t + 2, 0, 0, p);
    __builtin_amdgcn_s_barrier();
    asm volatile("s_waitcnt lgkmcnt(0)");
    __builtin_amdgcn_sched_barrier(0);
    __builtin_amdgcn_s_setprio(1);
#pragma unroll
    for (int m = 0; m < 4; ++m)
#pragma unroll
      for (int n = 0; n < 4; ++n)
        acc[m][n] = __builtin_amdgcn_mfma_f32_16x16x32_bf16(a[m], b[n], acc[m][n], 0, 0, 0);
    __builtin_amdgcn_s_setprio(0);
    __builtin_amdgcn_sched_barrier(0);
    __builtin_amdgcn_s_barrier();

    // phase 3: ksub1, m4..7 + tile-end counted vmcnt
#pragma unroll
    for (int m = 0; m < 4; ++m) a[m] = *(const bf16x8*)(A1 + awo + (4 + m) * 512);
    if (t + 2 < nk) stage(t + 2, 1, 1, p);
    __builtin_amdgcn_s_barrier();
    asm volatile("s_waitcnt lgkmcnt(0)");
    __builtin_amdgcn_sched_barrier(0);
    __builtin_amdgcn_s_setprio(1);
#pragma unroll
    for (int m = 0; m < 4; ++m)
#pragma unroll
      for (int n = 0; n < 4; ++n)
        acc[4 + m][n] = __builtin_amdgcn_mfma_f32_16x16x32_bf16(a[m], b[n], acc[4 + m][n], 0, 0, 0);
    __builtin_amdgcn_s_setprio(0);
    if (t < nk - 2) {
      asm volatile("s_waitcnt vmcnt(4)" ::: "memory");
    } else if (t == nk - 2) {
      asm volatile("s_waitcnt vmcnt(0)" ::: "memory");
    }
    __builtin_amdgcn_sched_barrier(0);
    __builtin_amdgcn_s_barrier();
  }
}

// ============ merged projection: QK (384 jobs) + VT (64 jobs), XCD-chunked ============
// flat f in [0,448): k=f&7 (XCD), c=f>>3 in [0,56).
//   c<48 : QK job  xa = 8k+(c&7) in [0,64), yb = c>>3 in [0,6)
//   c>=48: VT job  v  = 8k+(c-48) in [0,64)
__global__ __launch_bounds__(512, 2) void proj256(
    const unsigned short* __restrict__ emb_bf,
    const unsigned short* __restrict__ WT,
    const float* __restrict__ bias,
    unsigned short* __restrict__ QK,
    unsigned short* __restrict__ VT) {
  extern __shared__ unsigned short smem[];
  const int f = blockIdx.x;
  const int kx = f & 7, c = f >> 3;
  const int isQK = c < 48;
  long xa, yb;
  const unsigned short* Apan;
  const unsigned short* Bpan;
  if (isQK) {
    xa = kx * 8 + (c & 7); yb = c >> 3;
    Apan = emb_bf + xa * 256 * 768;
    Bpan = WT + yb * 256 * 768;
  } else {
    xa = 0; yb = kx * 8 + (c - 48);
    Apan = WT + (long)1536 * 768;
    Bpan = emb_bf + yb * 256 * 768;
  }
  f32x4 acc[8][4];
#pragma unroll
  for (int m = 0; m < 8; ++m)
#pragma unroll
    for (int n = 0; n < 4; ++n) acc[m][n] = f32x4{0.f, 0.f, 0.f, 0.f};

  k_loop_256(Apan, 768, Bpan, 768, 12, smem, acc);

  const int wid = threadIdx.x >> 6, lane = threadIdx.x & 63;
  const int wr = wid >> 2, wc = wid & 3;
  const int fr = lane & 15, fq = lane >> 4;
  if (isQK) {
#pragma unroll
    for (int m = 0; m < 8; ++m)
#pragma unroll
      for (int n = 0; n < 4; ++n) {
        const long mm = xa * 256 + wr * 128 + m * 16 + fq * 4;
        const long nn = yb * 256 + wc * 64 + n * 16 + fr;
        const float bb = bias[nn];
        f32x4 v = acc[m][n];
#pragma unroll
        for (int r = 0; r < 4; ++r) QK[(mm + r) * 1536 + nn] = f2bf(v[r] + bb);
      }
  } else {
#pragma unroll
    for (int m = 0; m < 8; ++m)
#pragma unroll
      for (int n = 0; n < 4; ++n) {
        const long mm = wr * 128 + m * 16 + fq * 4;   // DOUT row 0..255
        const long nn = yb * 256 + wc * 64 + n * 16 + fr;
        f32x4 v = acc[m][n];
#pragma unroll
        for (int r = 0; r < 4; ++r)
          VT[(mm + r) * 16384 + nn] = f2bf(v[r] + bias[1536 + mm + r]);
      }
  }
}

// ============ logits: per-batch Q*K^T * invTemp, XCD-chunked by batch pair ============
// flat f in [0,256): k=f&7 (XCD), c=f>>3 in [0,32).
//   bz = 2k + (c>>4); inner = c&15; bx = inner&3; by = inner>>2.
__global__ __launch_bounds__(512, 2) void logits256(
    const unsigned short* __restrict__ QK, float* __restrict__ attn) {
  extern __shared__ unsigned short smem[];
  const int f = blockIdx.x;
  const int kx = f & 7, c = f >> 3;
  const int bz = 2 * kx + (c >> 4);
  const int inner = c & 15, bx = inner & 3, by = inner >> 2;
  const unsigned short* Apan = QK + (long)bz * 1024 * 1536 + (long)bx * 256 * 1536;
  const unsigned short* Bpan = QK + 768 + (long)bz * 1024 * 1536 + (long)by * 256 * 1536;
  f32x4 acc[8][4];
#pragma unroll
  for (int m = 0; m < 8; ++m)
#pragma unroll
    for (int n = 0; n < 4; ++n) acc[m][n] = f32x4{0.f, 0.f, 0.f, 0.f};

  k_loop_256(Apan, 1536, Bpan, 1536, 12, smem, acc);

  const int wid = threadIdx.x >> 6, lane = threadIdx.x & 63;
  const int wr = wid >> 2, wc = wid & 3;
  const int fr = lane & 15, fq = lane >> 4;
  float* C = attn + (long)bz * 1024 * 1024;
#pragma unroll
  for (int m = 0; m < 8; ++m)
#pragma unroll
    for (int n = 0; n < 4; ++n) {
      const long mm = (long)bx * 256 + wr * 128 + m * 16 + fq * 4;
      const long nn = (long)by * 256 + wc * 64 + n * 16 + fr;
      f32x4 v = acc[m][n];
#pragma unroll
      for (int r = 0; r < 4; ++r) C[(mm + r) * 1024 + nn] = v[r] * INV_TEMP;
    }
}

// ---------------- masked row softmax + bf16 copy ----------------
// XCD-chunked: XCD k (f&7) handles rows [2048k, 2048k+2048) = batches {2k,2k+1},
// matching logits256's write map (attn rows still L2-warm).
__global__ __launch_bounds__(256) void softmax_rows(float* __restrict__ attn,
                                                    const int* __restrict__ mask,
                                                    unsigned short* __restrict__ attn_bf) {
  const int f = blockIdx.x;                      // 16384 = 8 * 2048
  const int row = ((f & 7) << 11) + (f >> 3);    // bijective
  const int b = row >> 10;
  float* p = attn + (long)row * 1024;
  const int tid = threadIdx.x, lane = tid & 63, wid = tid >> 6;
  float4 v = ((const float4*)p)[tid];
  int4 mk = ((const int4*)(mask + b * 1024))[tid];
  v.x = mk.x ? v.x : -1e9f;
  v.y = mk.y ? v.y : -1e9f;
  v.z = mk.z ? v.z : -1e9f;
  v.w = mk.w ? v.w : -1e9f;
  float mx = fmaxf(fmaxf(v.x, v.y), fmaxf(v.z, v.w));
#pragma unroll
  for (int off = 32; off; off >>= 1) mx = fmaxf(mx, __shfl_xor(mx, off));
  __shared__ float red[4];
  if (lane == 0) red[wid] = mx;
  __syncthreads();
  mx = fmaxf(fmaxf(red[0], red[1]), fmaxf(red[2], red[3]));
  float e0 = __expf(v.x - mx), e1 = __expf(v.y - mx);
  float e2 = __expf(v.z - mx), e3 = __expf(v.w - mx);
  float s = e0 + e1 + e2 + e3;
#pragma unroll
  for (int off = 32; off; off >>= 1) s += __shfl_xor(s, off);
  __shared__ float red2[4];
  if (lane == 0) red2[wid] = s;
  __syncthreads();
  s = red2[0] + red2[1] + red2[2] + red2[3];
  const float inv = 1.0f / s;
  float4 o;
  o.x = e0 * inv; o.y = e1 * inv; o.z = e2 * inv; o.w = e3 * inv;
  ((float4*)p)[tid] = o;
  u16x4 ob;
  ob[0] = f2bf(o.x); ob[1] = f2bf(o.y); ob[2] = f2bf(o.z); ob[3] = f2bf(o.w);
  *(u16x4*)(attn_bf + (long)row * 1024 + tid * 4) = ob;
}

// ======== PV: 128x64 tiles, 512 blocks, XCD-chunked by batch pair ========
// flat f in [0,512): k=f&7, c=f>>3 in [0,64); bz=2k+(c>>5); inner=c&31;
// tx=inner&7 (M-tile), ty=inner>>3 (N-tile). XCD k reads attnbf batches {2k,2k+1}
// (4 MB bf16, L2-fits) — matching softmax_rows' write map.
__global__ __launch_bounds__(256) void gemm_pv(
    const unsigned short* __restrict__ attnbf,   // [16][1024][1024]
    const unsigned short* __restrict__ VT,       // [256][16384]
    float* __restrict__ out) {                   // [16][1024][256]
  __shared__ unsigned short Ab[2][128 * 32];
  __shared__ unsigned short Bb[2][64 * 32];
  const int tid = threadIdx.x, wid = tid >> 6, lane = tid & 63;
  const int f = blockIdx.x;
  const int kxc = f & 7, c = f >> 3;
  const int bz = 2 * kxc + (c >> 5);
  const int inner = c & 31, tx = inner & 7, ty = inner >> 3;
  const unsigned short* A = attnbf + (long)bz * 1024 * 1024 + (long)tx * 128 * 1024;
  const unsigned short* BT = VT + (long)bz * 1024 + (long)ty * 64 * 16384;
  const int srow = lane >> 2;
  const int skk = (lane & 3) * 8;

  auto stage = [&](int buf, int kt) {
    const unsigned short* As = A + (long)kt * 32;
    const unsigned short* Bs = BT + (long)kt * 32;
#pragma unroll
    for (int i = 0; i < 2; ++i) {
      int ch = wid * 2 + i;
      async_copy16(As + (long)(ch * 16 + srow) * 1024 + skk, &Ab[buf][ch * 512]);
    }
    async_copy16(Bs + (long)(wid * 16 + srow) * 16384 + skk, &Bb[buf][wid * 512]);
  };

  f32x4 acc[4][2] = {};
  stage(0, 0);
  __syncthreads();
  int buf = 0;
  const int wr = wid >> 1, wc = wid & 1;
  const int fr = lane & 15, fq = lane >> 4;
  for (int kt = 0; kt < 32; ++kt) {
    if (kt + 1 < 32) stage(buf ^ 1, kt + 1);
    const unsigned short* Ap = &Ab[buf][(wr * 64 + fr) * 32 + fq * 8];
    const unsigned short* Bp = &Bb[buf][(wc * 32 + fr) * 32 + fq * 8];
    bf16x8 af[4], bfv[2];
#pragma unroll
    for (int mi = 0; mi < 4; ++mi) af[mi] = *(const bf16x8*)(Ap + mi * 16 * 32);
#pragma unroll
    for (int ni = 0; ni < 2; ++ni) bfv[ni] = *(const bf16x8*)(Bp + ni * 16 * 32);
#pragma unroll
    for (int mi = 0; mi < 4; ++mi)
#pragma unroll
      for (int ni = 0; ni < 2; ++ni)
        acc[mi][ni] = __builtin_amdgcn_mfma_f32_16x16x32_bf16(af[mi], bfv[ni], acc[mi][ni], 0, 0, 0);
    __syncthreads();
    buf ^= 1;
  }

  float* C = out + (long)bz * 1024 * 256;
  const long m0 = (long)tx * 128 + wr * 64;
  const long n0 = (long)ty * 64 + wc * 32;
#pragma unroll
  for (int mi = 0; mi < 4; ++mi)
#pragma unroll
    for (int ni = 0; ni < 2; ++ni) {
      const long m = m0 + mi * 16 + fq * 4;
      const long n = n0 + ni * 16 + fr;
      f32x4 v = acc[mi][ni];
#pragma unroll
      for (int r = 0; r < 4; ++r) C[(m + r) * 256 + n] = v[r];
    }
}

// ---------------- launch ----------------
extern "C" void kernel_launch(void* const* d_in, const int* in_sizes, int n_in,
                              void* d_out, int out_size, void* d_ws, size_t ws_size,
                              hipStream_t stream) {
  const float* emb = (const float*)d_in[0];
  const int* mask = (const int*)d_in[1];
  const int* isq = (const int*)d_in[2];
  const float* qWq = (const float*)d_in[3];  const float* qbq = (const float*)d_in[4];
  const float* qWk = (const float*)d_in[5];  const float* qbk = (const float*)d_in[6];
  const float* qWv = (const float*)d_in[7];  const float* qbv = (const float*)d_in[8];
  const float* dWq = (const float*)d_in[9];  const float* dbq = (const float*)d_in[10];
  const float* dWk = (const float*)d_in[11]; const float* dbk = (const float*)d_in[12];
  const float* dWv = (const float*)d_in[13]; const float* dbv = (const float*)d_in[14];

  char* ws = (char*)d_ws;
  unsigned short* emb_bf = (unsigned short*)ws;  ws += (size_t)16384 * 768 * 2;
  unsigned short* WT     = (unsigned short*)ws;  ws += (size_t)1792 * 768 * 2;
  float*          bias   = (float*)ws;           ws += (size_t)1792 * 4;
  unsigned short* QK     = (unsigned short*)ws;  ws += (size_t)16384 * 1536 * 2;
  unsigned short* VT     = (unsigned short*)ws;  ws += (size_t)256 * 16384 * 2;
  unsigned short* attnbf = (unsigned short*)ws;  ws += (size_t)16 * 1024 * 1024 * 2;

  float* out = (float*)d_out;                    // [16,1024,256]
  float* attn = out + (size_t)16 * 1024 * 256;   // [16,1024,1024]

  (void)hipFuncSetAttribute((const void*)&proj256,
                            hipFuncAttributeMaxDynamicSharedMemorySize, 131072);
  (void)hipFuncSetAttribute((const void*)&logits256,
                            hipFuncAttributeMaxDynamicSharedMemorySize, 131072);

  // pack_w FIRST so proj256 immediately follows pack_emb (emb L2-hot per XCD)
  hipLaunchKernelGGL(pack_w, dim3(1792), dim3(256), 0, stream, isq,
                     qWq, qbq, qWk, qbk, qWv, qbv, dWq, dbq, dWk, dbk, dWv, dbv, WT, bias);
  hipLaunchKernelGGL(pack_emb, dim3(6144), dim3(256), 0, stream, emb, emb_bf);
  // merged Q|K projection + V^T projection, XCD-chunked (matches pack_emb map)
  hipLaunchKernelGGL(proj256, dim3(448), dim3(512), 131072, stream,
                     emb_bf, WT, bias, QK, VT);
  // logits: per batch [1024,1024] = Q_b * K_b^T * invTemp, XCD-chunked (matches proj writes)
  hipLaunchKernelGGL(logits256, dim3(256), dim3(512), 131072, stream, QK, attn);
  // masked row softmax in-place + bf16 copy, XCD-chunked (matches logits writes)
  hipLaunchKernelGGL(softmax_rows, dim3(16384), dim3(256), 0, stream, attn, mask, attnbf);
  // out: per batch [1024,256] = attn_bf * V_b^T, XCD-chunked (matches softmax writes)
  hipLaunchKernelGGL(gemm_pv, dim3(512), dim3(256), 0, stream, attnbf, VT, out);
}